// Round 1
// baseline (832.927 us; speedup 1.0000x reference)
//
#include <hip/hip_runtime.h>

// entmax-1.5 along last dim, d = 1024.
// One 64-lane wave per row; 16 elements/lane held in registers (4x float4).
//
// tau solved by EXACT piecewise-quadratic root finding:
//   f(tau) = sum max(x/2 - tau, 0)^2 is convex, decreasing, piecewise
//   quadratic in tau. On the current active set A = {x > tau} with
//   K = |A|, s1 = sum(x - tau), s2 = sum((x - tau)^2), the root of the
//   current quadratic piece is
//     delta = (s2 - 1) / (s1 + sqrt(s1^2 - K*(s2 - 1)))   (stable form).
//   Jump there, recompute the active set, repeat. Lands exactly once the
//   support stabilizes -> typically 3-6 iterations (vs ~30-50 creeping
//   Newton steps). Invariants: tau in [-1, 0); xmax (=0 after shift) is
//   always active so s1 > 0; disc < 0 (piece has no root) => plain
//   Newton fallback; overshoot from the right self-corrects (convexity).

constexpr int D = 1024;
constexpr int WAVES_PER_BLOCK = 4; // 256 threads

__global__ __launch_bounds__(256) void entmax15_kernel(const float* __restrict__ x,
                                                       float* __restrict__ y,
                                                       int nrows) {
    const int wave = threadIdx.x >> 6;
    const int lane = threadIdx.x & 63;
    const int row  = blockIdx.x * WAVES_PER_BLOCK + wave;
    if (row >= nrows) return;

    const float4* xr = (const float4*)(x + (size_t)row * D);
    float4*       yr = (float4*)(y + (size_t)row * D);

    // Coalesced load: lane i takes float4 #(i + 64*j), j = 0..3  -> 1024 floats.
    float4 v[4];
#pragma unroll
    for (int j = 0; j < 4; ++j) v[j] = xr[lane + 64 * j];

    // x <- x/2 ; row max
    float m = -3.4e38f;
#pragma unroll
    for (int j = 0; j < 4; ++j) {
        v[j].x *= 0.5f; v[j].y *= 0.5f; v[j].z *= 0.5f; v[j].w *= 0.5f;
        m = fmaxf(m, fmaxf(fmaxf(v[j].x, v[j].y), fmaxf(v[j].z, v[j].w)));
    }
#pragma unroll
    for (int off = 32; off >= 1; off >>= 1) m = fmaxf(m, __shfl_xor(m, off));

#pragma unroll
    for (int j = 0; j < 4; ++j) { v[j].x -= m; v[j].y -= m; v[j].z -= m; v[j].w -= m; }

    // Exact piece solve. Start tau = -1 (f(-1) >= 1 since xmax = 0).
    float tau = -1.0f;
    for (int it = 0; it < 16; ++it) {
        float s1 = 0.f, s2 = 0.f, kc = 0.f;
#pragma unroll
        for (int j = 0; j < 4; ++j) {
            float t;
            t = fmaxf(v[j].x - tau, 0.f); s1 += t; s2 = fmaf(t, t, s2); kc += (t > 0.f) ? 1.f : 0.f;
            t = fmaxf(v[j].y - tau, 0.f); s1 += t; s2 = fmaf(t, t, s2); kc += (t > 0.f) ? 1.f : 0.f;
            t = fmaxf(v[j].z - tau, 0.f); s1 += t; s2 = fmaf(t, t, s2); kc += (t > 0.f) ? 1.f : 0.f;
            t = fmaxf(v[j].w - tau, 0.f); s1 += t; s2 = fmaf(t, t, s2); kc += (t > 0.f) ? 1.f : 0.f;
        }
#pragma unroll
        for (int off = 32; off >= 1; off >>= 1) {
            s1 += __shfl_xor(s1, off);
            s2 += __shfl_xor(s2, off);
            kc += __shfl_xor(kc, off);
        }
        const float diff = s2 - 1.0f;                  // residual (wave-uniform)
        if (fabsf(diff) <= 1e-6f) break;
        const float disc = fmaf(-kc, diff, s1 * s1);   // s1^2 - K*(s2-1)
        float delta;
        if (disc >= 0.f) delta = diff / (s1 + __builtin_sqrtf(disc)); // exact piece root
        else             delta = diff / (2.0f * s1);                  // Newton fallback
        const float tnew = tau + delta;
        if (tnew == tau) break;                        // fp fixed point
        tau = tnew;
    }

    // y = max(x - tau, 0)^2, coalesced float4 stores.
#pragma unroll
    for (int j = 0; j < 4; ++j) {
        float4 o; float t;
        t = fmaxf(v[j].x - tau, 0.f); o.x = t * t;
        t = fmaxf(v[j].y - tau, 0.f); o.y = t * t;
        t = fmaxf(v[j].z - tau, 0.f); o.z = t * t;
        t = fmaxf(v[j].w - tau, 0.f); o.w = t * t;
        yr[lane + 64 * j] = o;
    }
}

extern "C" void kernel_launch(void* const* d_in, const int* in_sizes, int n_in,
                              void* d_out, int out_size, void* d_ws, size_t ws_size,
                              hipStream_t stream) {
    const float* x = (const float*)d_in[0];
    float*       y = (float*)d_out;
    const int nrows = in_sizes[0] / D;              // 131072
    const int blocks = (nrows + WAVES_PER_BLOCK - 1) / WAVES_PER_BLOCK;
    entmax15_kernel<<<blocks, 256, 0, stream>>>(x, y, nrows);
}

// Round 2
// 807.037 us; speedup vs baseline: 1.0321x; 1.0321x over previous
//
#include <hip/hip_runtime.h>

// entmax-1.5 along last dim, d = 1024.
// One 64-lane wave per row; 16 elements/lane in registers (4x f32x4).
//
// tau solved by exact piecewise-quadratic root jumps on
//   f(tau) = sum max(x/2 - tau, 0)^2 = 1
// (convex, decreasing, piecewise quadratic). On the active set A = {x/2 > tau},
// K = |A|, s1 = sum(x/2 - tau), s2 = sum((x/2 - tau)^2):
//   delta = (s2 - 1) / (s1 + sqrt(s1^2 - K*(s2 - 1)))   (stable conjugate form)
// Jumps are monotone from the left (piece quadratic >= f for tau' > tau, so the
// piece root never overshoots f's root) => tau is non-decreasing, tau >= tau0,
// and xmax is always active (s1 >= 1 at convergence since s2 = 1).
//
// tau kept in raw/2 coordinates: t = fma(0.5, x, -tau), tau0 = m/2 - 1.
// No pre-scale/pre-shift passes; support count K via ballot+popcount (SALU,
// wave-uniform, no butterfly).

constexpr int D = 1024;
constexpr int WAVES_PER_BLOCK = 4; // 256 threads

using f32x4 = __attribute__((ext_vector_type(4))) float;

__global__ __launch_bounds__(256) void entmax15_kernel(const float* __restrict__ x,
                                                       float* __restrict__ y,
                                                       int nrows) {
    const int wave = threadIdx.x >> 6;
    const int lane = threadIdx.x & 63;
    const int row  = blockIdx.x * WAVES_PER_BLOCK + wave;
    if (row >= nrows) return;

    const f32x4* xr = (const f32x4*)(x + (size_t)row * D);
    f32x4*       yr = (f32x4*)(y + (size_t)row * D);

    // Coalesced: lane i takes f32x4 #(i + 64*j), j = 0..3 -> 1024 floats/row.
    f32x4 v[4];
#pragma unroll
    for (int j = 0; j < 4; ++j) v[j] = __builtin_nontemporal_load(xr + lane + 64 * j);

    // Row max of raw x.
    float m = -3.4e38f;
#pragma unroll
    for (int j = 0; j < 4; ++j)
        m = fmaxf(m, fmaxf(fmaxf(v[j].x, v[j].y), fmaxf(v[j].z, v[j].w)));
#pragma unroll
    for (int off = 32; off >= 1; off >>= 1) m = fmaxf(m, __shfl_xor(m, off));

    // tau0 = m/2 - 1 (f(tau0) >= 1 since the max element contributes 1).
    float tau = fmaf(0.5f, m, -1.0f);
#pragma unroll 1
    for (int it = 0; it < 10; ++it) {
        float s1 = 0.f, s2 = 0.f;
        int kc = 0;
#pragma unroll
        for (int j = 0; j < 4; ++j) {
            float t;
            t = fmaxf(fmaf(0.5f, v[j].x, -tau), 0.f); s1 += t; s2 = fmaf(t, t, s2);
            kc += (int)__popcll(__ballot(t > 0.f));
            t = fmaxf(fmaf(0.5f, v[j].y, -tau), 0.f); s1 += t; s2 = fmaf(t, t, s2);
            kc += (int)__popcll(__ballot(t > 0.f));
            t = fmaxf(fmaf(0.5f, v[j].z, -tau), 0.f); s1 += t; s2 = fmaf(t, t, s2);
            kc += (int)__popcll(__ballot(t > 0.f));
            t = fmaxf(fmaf(0.5f, v[j].w, -tau), 0.f); s1 += t; s2 = fmaf(t, t, s2);
            kc += (int)__popcll(__ballot(t > 0.f));
        }
        // Wave reduction for s1, s2 (kc is already wave-uniform via ballot).
#pragma unroll
        for (int off = 32; off >= 1; off >>= 1) {
            s1 += __shfl_xor(s1, off);
            s2 += __shfl_xor(s2, off);
        }
        const float diff = s2 - 1.0f;                  // wave-uniform residual
        if (fabsf(diff) <= 4e-6f) break;               // fp32 noise floor of 1024-term sum
        const float K    = (float)kc;
        const float disc = fmaf(-K, diff, s1 * s1);    // s1^2 - K*(s2-1)
        const float delta = (disc > 0.f) ? (diff / (s1 + __builtin_sqrtf(disc)))
                                         : (diff / (2.0f * s1)); // Newton fallback
        const float tnew = tau + delta;
        if (tnew == tau) break;                        // fp fixed point
        tau = tnew;
    }

    // y = max(x/2 - tau, 0)^2, coalesced nontemporal stores.
#pragma unroll
    for (int j = 0; j < 4; ++j) {
        f32x4 o; float t;
        t = fmaxf(fmaf(0.5f, v[j].x, -tau), 0.f); o.x = t * t;
        t = fmaxf(fmaf(0.5f, v[j].y, -tau), 0.f); o.y = t * t;
        t = fmaxf(fmaf(0.5f, v[j].z, -tau), 0.f); o.z = t * t;
        t = fmaxf(fmaf(0.5f, v[j].w, -tau), 0.f); o.w = t * t;
        __builtin_nontemporal_store(o, yr + lane + 64 * j);
    }
}

extern "C" void kernel_launch(void* const* d_in, const int* in_sizes, int n_in,
                              void* d_out, int out_size, void* d_ws, size_t ws_size,
                              hipStream_t stream) {
    const float* x = (const float*)d_in[0];
    float*       y = (float*)d_out;
    const int nrows = in_sizes[0] / D;              // 131072
    const int blocks = (nrows + WAVES_PER_BLOCK - 1) / WAVES_PER_BLOCK;
    entmax15_kernel<<<blocks, 256, 0, stream>>>(x, y, nrows);
}